// Round 5
// baseline (347.228 us; speedup 1.0000x reference)
//
#include <hip/hip_runtime.h>
#include <math.h>

// Problem constants: B=16, C=512, T=1024, C8=64.
constexpr int Bc = 16;
constexpr int Cc = 512;
constexpr int Tc = 1024;

typedef unsigned short u16;
typedef __attribute__((ext_vector_type(8))) short bf16x8;
typedef __attribute__((ext_vector_type(4))) float floatx4;

__device__ inline u16 f2bf(float f) {
    union { float f; unsigned u; } v; v.f = f;
    unsigned r = v.u + 0x7FFFu + ((v.u >> 16) & 1u);   // RNE
    return (u16)(r >> 16);
}

// Async global->LDS, 16 B per lane. LDS dest = wave-uniform base + lane*16.
__device__ inline void async16(const void* g, void* l) {
    __builtin_amdgcn_global_load_lds(
        (const __attribute__((address_space(1))) unsigned*)g,
        (__attribute__((address_space(3))) unsigned*)l, 16, 0, 0);
}

// ---------------------------------------------------------------------------
// Kernel A: W fp32 -> wb bf16 [640][512]; rows 0-63=qw, 64-127=kw, 128-639=vw.
// ---------------------------------------------------------------------------
__global__ __launch_bounds__(256) void wconv_kernel(
    const float* __restrict__ qw, const float* __restrict__ kw,
    const float* __restrict__ vw, u16* __restrict__ wb)
{
    int i4 = blockIdx.x * 256 + threadIdx.x;   // 0..81919 (float4 index)
    int e  = i4 * 4;
    int row = e >> 9, col = e & 511;
    const float* src = (row < 64)  ? qw + (size_t)row * 512 + col
                     : (row < 128) ? kw + (size_t)(row - 64) * 512 + col
                                   : vw + (size_t)(row - 128) * 512 + col;
    float4 v = *(const float4*)src;
    ushort4 o = { f2bf(v.x), f2bf(v.y), f2bf(v.z), f2bf(v.w) };
    *(ushort4*)(wb + e) = o;
}

// ---------------------------------------------------------------------------
// Kernel B: x[b][c][t] fp32 -> xt[(b*T + t)][c] bf16 (c contiguous).
// 64x64 tiles via LDS transpose; xs pad 65 gives 2-way (free) banks both ways.
// ---------------------------------------------------------------------------
__global__ __launch_bounds__(256) void xtrans_kernel(
    const float* __restrict__ x, u16* __restrict__ xt)
{
    const int b = blockIdx.z, c0 = blockIdx.y * 64, t0 = blockIdx.x * 64;
    const int tid = threadIdx.x;
    __shared__ float xs[64][65];

    const float* xb = x + ((size_t)(b * Cc + c0)) * Tc + t0;
    #pragma unroll
    for (int r = 0; r < 4; ++r) {
        int f = tid + 256 * r;
        int c = f >> 4, tf = f & 15;
        float4 v = *(const float4*)(xb + (size_t)c * Tc + tf * 4);
        xs[c][tf * 4 + 0] = v.x; xs[c][tf * 4 + 1] = v.y;
        xs[c][tf * 4 + 2] = v.z; xs[c][tf * 4 + 3] = v.w;
    }
    __syncthreads();
    u16* xo = xt + ((size_t)b * Tc + t0) * Cc + c0;
    #pragma unroll
    for (int r = 0; r < 4; ++r) {
        int t  = (tid >> 4) + 16 * r;
        int cc = tid & 15;
        ushort4 o;
        o.x = f2bf(xs[cc * 4 + 0][t]); o.y = f2bf(xs[cc * 4 + 1][t]);
        o.z = f2bf(xs[cc * 4 + 2][t]); o.w = f2bf(xs[cc * 4 + 3][t]);
        *(ushort4*)(xo + (size_t)t * Cc + cc * 4) = o;
    }
}

// ---------------------------------------------------------------------------
// Kernel C: MFMA projection GEMM. D[n][t] = wb[n][c] * xt[t][c], K=512.
// Block 128n x 128t, BK=64, 4 waves each 64n x 64t (16 accs).
// __launch_bounds__(256,2): 256-VGPR budget — acc(64)+frags(32)+addr fits,
// prevents scratch spill (R4 post-mortem: spills dominated HBM writes).
// ---------------------------------------------------------------------------
__global__ __launch_bounds__(256, 2) void proj_kernel(
    const u16* __restrict__ wb, const u16* __restrict__ xt,
    const float* __restrict__ qb, const float* __restrict__ kb,
    const float* __restrict__ vb,
    u16* __restrict__ qt, u16* __restrict__ kt, u16* __restrict__ vc)
{
    const int b   = blockIdx.z;
    const int t0  = blockIdx.x * 128;
    const int n0  = blockIdx.y * 128;
    const int tid = threadIdx.x;
    const int w = tid >> 6, lane = tid & 63;
    const int l15 = lane & 15, q = lane >> 4;
    const int r8 = lane >> 3, h = lane & 7;
    const int nh = w >> 1, th = w & 1;      // wave quadrant: 64n x 64t

    __shared__ u16 As[128 * 64];            // W tile   (swizzled rows)
    __shared__ u16 Bs[128 * 64];            // xt tile  (swizzled rows)

    floatx4 acc[4][4];
    #pragma unroll
    for (int i = 0; i < 4; ++i)
        #pragma unroll
        for (int j = 0; j < 4; ++j) acc[i][j] = (floatx4){0.f, 0.f, 0.f, 0.f};

    const u16* wbase = wb + (size_t)n0 * Cc;
    const u16* xbase = xt + ((size_t)b * Tc + t0) * Cc;

    for (int k0 = 0; k0 < Cc; k0 += 64) {
        #pragma unroll
        for (int i = 0; i < 4; ++i) {
            int row  = w * 32 + i * 8 + r8;        // per-lane tile row
            int gcol = k0 + (((h + row) & 7) << 3);
            async16(wbase + (size_t)row * Cc + gcol, &As[(w * 32 + i * 8) * 64]);
            async16(xbase + (size_t)row * Cc + gcol, &Bs[(w * 32 + i * 8) * 64]);
        }
        asm volatile("s_waitcnt vmcnt(0)" ::: "memory");
        __syncthreads();

        #pragma unroll
        for (int ko = 0; ko < 64; ko += 32) {
            bf16x8 af[4], bf[4];
            const int cc = (ko >> 3) + q;
            #pragma unroll
            for (int i = 0; i < 4; ++i) {
                int row = nh * 64 + i * 16 + l15;
                af[i] = *(const bf16x8*)&As[row * 64 + (((cc - row) & 7) << 3)];
            }
            #pragma unroll
            for (int j = 0; j < 4; ++j) {
                int row = th * 64 + j * 16 + l15;
                bf[j] = *(const bf16x8*)&Bs[row * 64 + (((cc - row) & 7) << 3)];
            }
            #pragma unroll
            for (int i = 0; i < 4; ++i)
                #pragma unroll
                for (int j = 0; j < 4; ++j)
                    acc[i][j] = __builtin_amdgcn_mfma_f32_16x16x32_bf16(
                        af[i], bf[j], acc[i][j], 0, 0, 0);
        }
        __syncthreads();
    }

    if (n0 >= 128) {
        // V rows: D[n][t] col=t=l15 -> vc[b][c][t] stores are t-coalesced.
        const int c_base = n0 - 128 + nh * 64;
        u16* vbb = vc + (size_t)b * Cc * Tc;
        #pragma unroll
        for (int i = 0; i < 4; ++i) {
            #pragma unroll
            for (int rr = 0; rr < 4; ++rr) {
                int c = c_base + i * 16 + q * 4 + rr;
                float bias = vb[c];
                #pragma unroll
                for (int j = 0; j < 4; ++j) {
                    int t = t0 + th * 64 + j * 16 + l15;
                    vbb[((size_t)c << 10) + t] = f2bf(acc[i][j][rr] + bias);
                }
            }
        }
    } else {
        // Q/K rows (block n0==0): wave nh==0 -> Q, nh==1 -> K.
        const float* bias_p = nh ? kb : qb;
        u16* dst = nh ? kt : qt;
        u16* reg = ((w & 2) ? Bs : As) + (w & 1) * 4096;  // 32*72=2304 <= 4096
        #pragma unroll 1
        for (int jh = 0; jh < 2; ++jh) {
            #pragma unroll
            for (int j2 = 0; j2 < 2; ++j2) {
                int j = jh * 2 + j2;
                int t_loc = j2 * 16 + l15;
                #pragma unroll
                for (int i = 0; i < 4; ++i) {
                    ushort4 o;
                    float b0 = bias_p[i * 16 + q * 4 + 0];
                    float b1 = bias_p[i * 16 + q * 4 + 1];
                    float b2 = bias_p[i * 16 + q * 4 + 2];
                    float b3 = bias_p[i * 16 + q * 4 + 3];
                    o.x = f2bf(acc[i][j][0] + b0);
                    o.y = f2bf(acc[i][j][1] + b1);
                    o.z = f2bf(acc[i][j][2] + b2);
                    o.w = f2bf(acc[i][j][3] + b3);
                    *(ushort4*)&reg[t_loc * 72 + i * 16 + q * 4] = o;
                }
            }
            const int cc8 = lane & 7, tb = lane >> 3;
            #pragma unroll
            for (int rr2 = 0; rr2 < 4; ++rr2) {
                int t32 = tb * 4 + rr2;
                bf16x8 vv = *(const bf16x8*)&reg[t32 * 72 + cc8 * 8];
                int t = t0 + th * 64 + jh * 32 + t32;
                *(bf16x8*)(dst + ((size_t)b * Tc + t) * 64 + cc8 * 8) = vv;
            }
        }
    }
}

// ---------------------------------------------------------------------------
// Kernel D: fused MFMA attention v4 = v3 + __launch_bounds__(256,2).
// R4 post-mortem: default VGPR budget (72) forced per-iteration scratch
// spills -> 933 MB HBM writes. 256-VGPR budget holds acc(64)+operands live;
// 512 blocks / 256 CUs = 2 blocks/CU = exactly co-resident.
// ---------------------------------------------------------------------------
__global__ __launch_bounds__(256, 2) void attn_kernel(
    const float* __restrict__ x,
    const u16* __restrict__ qt, const u16* __restrict__ kt,
    const u16* __restrict__ vc, const float* __restrict__ gp,
    float* __restrict__ out)
{
    const int tid = threadIdx.x, lane = tid & 63, w = tid >> 6;
    const int l15 = lane & 15, q = lane >> 4;
    // XCD swizzle: xcd = l&7; 4 (b,by) combos per XCD; 16 bx each, ids mod 8.
    const int l    = blockIdx.x;           // 0..511
    const int xcd  = l & 7, slot = l >> 3;
    const int combo = xcd * 4 + (slot >> 4);
    const int bx = slot & 15;
    const int b  = combo >> 1;
    const int by = combo & 1;
    const int t0 = bx * 64;
    const int cb = by * 256;

    __shared__ u16   P[2][4][16][40];   // [buf][t-subtile][t'][s pad40] 10 KB
    __shared__ float lrow[64];
    __shared__ float tr2[4][16][68];    // per-wave [c][t] epilogue staging

    // Q B-frags for this wave's t-subtile (t = t0 + w*16 + l15).
    const u16* qp = qt + ((size_t)b * Tc + t0 + w * 16 + l15) * 64 + q * 8;
    const bf16x8 qf0 = *(const bf16x8*)qp;
    const bf16x8 qf1 = *(const bf16x8*)(qp + 32);

    const u16* ktb = kt + (size_t)b * Tc * 64;
    const u16* vbb = vc + ((size_t)(b * Cc + cb + w * 64)) * Tc;

    floatx4 acc[4][4];                  // [tt][cg]
    #pragma unroll
    for (int i = 0; i < 4; ++i)
        #pragma unroll
        for (int j = 0; j < 4; ++j) acc[i][j] = (floatx4){0.f, 0.f, 0.f, 0.f};
    float lsum = 0.f;

    int buf = 0;
    #pragma unroll 1
    for (int s0 = 0; s0 < Tc; s0 += 32, buf ^= 1) {
        const u16* kp = ktb + (size_t)(s0 + l15) * 64 + q * 8;
        bf16x8 k00 = *(const bf16x8*)kp;
        bf16x8 k01 = *(const bf16x8*)(kp + 32);
        bf16x8 k10 = *(const bf16x8*)(kp + 1024);
        bf16x8 k11 = *(const bf16x8*)(kp + 1024 + 32);

        bf16x8 vf[4];
        const u16* vp = vbb + (size_t)l15 * Tc + s0 + q * 8;
        #pragma unroll
        for (int cg = 0; cg < 4; ++cg)
            vf[cg] = *(const bf16x8*)(vp + (size_t)cg * 16 * Tc);

        floatx4 e0 = (floatx4){0.f, 0.f, 0.f, 0.f};
        floatx4 e1 = (floatx4){0.f, 0.f, 0.f, 0.f};
        e0 = __builtin_amdgcn_mfma_f32_16x16x32_bf16(k00, qf0, e0, 0, 0, 0);
        e0 = __builtin_amdgcn_mfma_f32_16x16x32_bf16(k01, qf1, e0, 0, 0, 0);
        e1 = __builtin_amdgcn_mfma_f32_16x16x32_bf16(k10, qf0, e1, 0, 0, 0);
        e1 = __builtin_amdgcn_mfma_f32_16x16x32_bf16(k11, qf1, e1, 0, 0, 0);

        float p0[4], p1[4];
        #pragma unroll
        for (int r = 0; r < 4; ++r) { p0[r] = __expf(e0[r]); p1[r] = __expf(e1[r]); }
        lsum += p0[0] + p0[1] + p0[2] + p0[3] + p1[0] + p1[1] + p1[2] + p1[3];

        ushort4 w0 = { f2bf(p0[0]), f2bf(p0[1]), f2bf(p0[2]), f2bf(p0[3]) };
        ushort4 w1 = { f2bf(p1[0]), f2bf(p1[1]), f2bf(p1[2]), f2bf(p1[3]) };
        *(ushort4*)&P[buf][w][l15][q * 4]      = w0;
        *(ushort4*)&P[buf][w][l15][16 + q * 4] = w1;
        __syncthreads();

        #pragma unroll
        for (int tt = 0; tt < 4; ++tt) {
            bf16x8 pf = *(const bf16x8*)&P[buf][tt][l15][q * 8];
            #pragma unroll
            for (int cg = 0; cg < 4; ++cg)
                acc[tt][cg] = __builtin_amdgcn_mfma_f32_16x16x32_bf16(
                    pf, vf[cg], acc[tt][cg], 0, 0, 0);
        }
    }

    // l per t: reduce the 4 disjoint q-partials, share across waves.
    lsum += __shfl_xor(lsum, 16);
    lsum += __shfl_xor(lsum, 32);
    if (lane < 16) lrow[w * 16 + lane] = lsum;
    __syncthreads();

    const float g = gp[0];
    float sc[4][4];
    #pragma unroll
    for (int tt = 0; tt < 4; ++tt)
        #pragma unroll
        for (int rr = 0; rr < 4; ++rr)
            sc[tt][rr] = g / lrow[tt * 16 + q * 4 + rr];

    // Epilogue: per 16c-chunk cg: stage [c=l15][t 64] (float4 over rr), then
    // float4 read + x-add + store (full 128 B lines per instruction).
    const float* xb = x   + ((size_t)(b * Cc + cb + w * 64)) * Tc + t0;
    float*       ob = out + ((size_t)(b * Cc + cb + w * 64)) * Tc + t0;
    #pragma unroll 1
    for (int cg = 0; cg < 4; ++cg) {
        #pragma unroll
        for (int tt = 0; tt < 4; ++tt) {
            float4 vv;
            vv.x = acc[tt][cg][0] * sc[tt][0];
            vv.y = acc[tt][cg][1] * sc[tt][1];
            vv.z = acc[tt][cg][2] * sc[tt][2];
            vv.w = acc[tt][cg][3] * sc[tt][3];
            *(float4*)&tr2[w][l15][tt * 16 + q * 4] = vv;
        }
        #pragma unroll
        for (int i = 0; i < 4; ++i) {
            int cr = i * 4 + (lane >> 4);       // c within chunk
            int t4 = (lane & 15) * 4;
            float4 vv = *(const float4*)&tr2[w][cr][t4];
            size_t go = (size_t)(cg * 16 + cr) * Tc + t4;
            float4 xv = *(const float4*)(xb + go);
            vv.x += xv.x; vv.y += xv.y; vv.z += xv.z; vv.w += xv.w;
            *(float4*)(ob + go) = vv;
        }
        __builtin_amdgcn_wave_barrier();   // keep write(cg+1) after read(cg)
    }
}

extern "C" void kernel_launch(void* const* d_in, const int* in_sizes, int n_in,
                              void* d_out, int out_size, void* d_ws, size_t ws_size,
                              hipStream_t stream) {
    const float* x     = (const float*)d_in[0];
    const float* qw    = (const float*)d_in[1];
    const float* qbias = (const float*)d_in[2];
    const float* kw    = (const float*)d_in[3];
    const float* kbias = (const float*)d_in[4];
    const float* vw    = (const float*)d_in[5];
    const float* vbias = (const float*)d_in[6];
    const float* gamma = (const float*)d_in[7];
    float* out = (float*)d_out;

    // ws (bf16): wb[640][512] | xt[B*T][512] | qt[B*T][64] | kt[B*T][64] | vc[B][C][T]
    u16* wb = (u16*)d_ws;
    u16* xt = wb + (size_t)640 * 512;
    u16* qt = xt + (size_t)Bc * Tc * Cc;
    u16* kt = qt + (size_t)Bc * Tc * 64;
    u16* vc = kt + (size_t)Bc * Tc * 64;

    wconv_kernel<<<320, 256, 0, stream>>>(qw, kw, vw, wb);
    xtrans_kernel<<<dim3(Tc / 64, Cc / 64, Bc), 256, 0, stream>>>(x, xt);
    proj_kernel<<<dim3(Tc / 128, 5, Bc), 256, 0, stream>>>(
        wb, xt, qbias, kbias, vbias, qt, kt, vc);
    attn_kernel<<<dim3(512), 256, 0, stream>>>(
        x, qt, kt, vc, gamma, out);
}

// Round 6
// 178.452 us; speedup vs baseline: 1.9458x; 1.9458x over previous
//
#include <hip/hip_runtime.h>
#include <math.h>

// Problem constants: B=16, C=512, T=1024, C8=64.
constexpr int Bc = 16;
constexpr int Cc = 512;
constexpr int Tc = 1024;

typedef unsigned short u16;
typedef __attribute__((ext_vector_type(8))) short bf16x8;
typedef __attribute__((ext_vector_type(4))) float floatx4;

__device__ inline u16 f2bf(float f) {
    union { float f; unsigned u; } v; v.f = f;
    unsigned r = v.u + 0x7FFFu + ((v.u >> 16) & 1u);   // RNE
    return (u16)(r >> 16);
}

// Async global->LDS, 16 B per lane. LDS dest = wave-uniform base + lane*16.
__device__ inline void async16(const void* g, void* l) {
    __builtin_amdgcn_global_load_lds(
        (const __attribute__((address_space(1))) unsigned*)g,
        (__attribute__((address_space(3))) unsigned*)l, 16, 0, 0);
}

// ---------------------------------------------------------------------------
// Kernel A: W fp32 -> wb bf16 [640][512]; rows 0-63=qw, 64-127=kw, 128-639=vw.
// ---------------------------------------------------------------------------
__global__ __launch_bounds__(256) void wconv_kernel(
    const float* __restrict__ qw, const float* __restrict__ kw,
    const float* __restrict__ vw, u16* __restrict__ wb)
{
    int i4 = blockIdx.x * 256 + threadIdx.x;   // 0..81919 (float4 index)
    int e  = i4 * 4;
    int row = e >> 9, col = e & 511;
    const float* src = (row < 64)  ? qw + (size_t)row * 512 + col
                     : (row < 128) ? kw + (size_t)(row - 64) * 512 + col
                                   : vw + (size_t)(row - 128) * 512 + col;
    float4 v = *(const float4*)src;
    ushort4 o = { f2bf(v.x), f2bf(v.y), f2bf(v.z), f2bf(v.w) };
    *(ushort4*)(wb + e) = o;
}

// ---------------------------------------------------------------------------
// Kernel B: x[b][c][t] fp32 -> xt[(b*T + t)][c] bf16 (c contiguous).
// 64x64 tiles via LDS transpose; xs pad 65 gives 2-way (free) banks both ways.
// ---------------------------------------------------------------------------
__global__ __launch_bounds__(256) void xtrans_kernel(
    const float* __restrict__ x, u16* __restrict__ xt)
{
    const int b = blockIdx.z, c0 = blockIdx.y * 64, t0 = blockIdx.x * 64;
    const int tid = threadIdx.x;
    __shared__ float xs[64][65];

    const float* xb = x + ((size_t)(b * Cc + c0)) * Tc + t0;
    #pragma unroll
    for (int r = 0; r < 4; ++r) {
        int f = tid + 256 * r;
        int c = f >> 4, tf = f & 15;
        float4 v = *(const float4*)(xb + (size_t)c * Tc + tf * 4);
        xs[c][tf * 4 + 0] = v.x; xs[c][tf * 4 + 1] = v.y;
        xs[c][tf * 4 + 2] = v.z; xs[c][tf * 4 + 3] = v.w;
    }
    __syncthreads();
    u16* xo = xt + ((size_t)b * Tc + t0) * Cc + c0;
    #pragma unroll
    for (int r = 0; r < 4; ++r) {
        int t  = (tid >> 4) + 16 * r;
        int cc = tid & 15;
        ushort4 o;
        o.x = f2bf(xs[cc * 4 + 0][t]); o.y = f2bf(xs[cc * 4 + 1][t]);
        o.z = f2bf(xs[cc * 4 + 2][t]); o.w = f2bf(xs[cc * 4 + 3][t]);
        *(ushort4*)(xo + (size_t)t * Cc + cc * 4) = o;
    }
}

// ---------------------------------------------------------------------------
// Kernel C: MFMA projection GEMM. D[n][t] = wb[n][c] * xt[t][c], K=512.
// Block 128n x 128t, BK=64, 4 waves each 64n x 64t (16 accs).
// NOTE: every index into acc[][] must be a compile-time constant — a runtime
// index forces the alloca to scratch (R5 post-mortem: 850 MB spill traffic).
// ---------------------------------------------------------------------------
__global__ __launch_bounds__(256, 2) void proj_kernel(
    const u16* __restrict__ wb, const u16* __restrict__ xt,
    const float* __restrict__ qb, const float* __restrict__ kb,
    const float* __restrict__ vb,
    u16* __restrict__ qt, u16* __restrict__ kt, u16* __restrict__ vc)
{
    const int b   = blockIdx.z;
    const int t0  = blockIdx.x * 128;
    const int n0  = blockIdx.y * 128;
    const int tid = threadIdx.x;
    const int w = tid >> 6, lane = tid & 63;
    const int l15 = lane & 15, q = lane >> 4;
    const int r8 = lane >> 3, h = lane & 7;
    const int nh = w >> 1, th = w & 1;      // wave quadrant: 64n x 64t

    __shared__ u16 As[128 * 64];            // W tile   (swizzled rows)
    __shared__ u16 Bs[128 * 64];            // xt tile  (swizzled rows)

    floatx4 acc[4][4];
    #pragma unroll
    for (int i = 0; i < 4; ++i)
        #pragma unroll
        for (int j = 0; j < 4; ++j) acc[i][j] = (floatx4){0.f, 0.f, 0.f, 0.f};

    const u16* wbase = wb + (size_t)n0 * Cc;
    const u16* xbase = xt + ((size_t)b * Tc + t0) * Cc;

    for (int k0 = 0; k0 < Cc; k0 += 64) {
        #pragma unroll
        for (int i = 0; i < 4; ++i) {
            int row  = w * 32 + i * 8 + r8;        // per-lane tile row
            int gcol = k0 + (((h + row) & 7) << 3);
            async16(wbase + (size_t)row * Cc + gcol, &As[(w * 32 + i * 8) * 64]);
            async16(xbase + (size_t)row * Cc + gcol, &Bs[(w * 32 + i * 8) * 64]);
        }
        asm volatile("s_waitcnt vmcnt(0)" ::: "memory");
        __syncthreads();

        #pragma unroll
        for (int ko = 0; ko < 64; ko += 32) {
            bf16x8 af[4], bf[4];
            const int cc = (ko >> 3) + q;
            #pragma unroll
            for (int i = 0; i < 4; ++i) {
                int row = nh * 64 + i * 16 + l15;
                af[i] = *(const bf16x8*)&As[row * 64 + (((cc - row) & 7) << 3)];
            }
            #pragma unroll
            for (int j = 0; j < 4; ++j) {
                int row = th * 64 + j * 16 + l15;
                bf[j] = *(const bf16x8*)&Bs[row * 64 + (((cc - row) & 7) << 3)];
            }
            #pragma unroll
            for (int i = 0; i < 4; ++i)
                #pragma unroll
                for (int j = 0; j < 4; ++j)
                    acc[i][j] = __builtin_amdgcn_mfma_f32_16x16x32_bf16(
                        af[i], bf[j], acc[i][j], 0, 0, 0);
        }
        __syncthreads();
    }

    if (n0 >= 128) {
        // V rows: D[n][t] col=t=l15 -> vc[b][c][t] stores are t-coalesced.
        const int c_base = n0 - 128 + nh * 64;
        u16* vbb = vc + (size_t)b * Cc * Tc;
        #pragma unroll
        for (int i = 0; i < 4; ++i) {
            #pragma unroll
            for (int rr = 0; rr < 4; ++rr) {
                int c = c_base + i * 16 + q * 4 + rr;
                float bias = vb[c];
                #pragma unroll
                for (int j = 0; j < 4; ++j) {
                    int t = t0 + th * 64 + j * 16 + l15;
                    vbb[((size_t)c << 10) + t] = f2bf(acc[i][j][rr] + bias);
                }
            }
        }
    } else {
        // Q/K rows (block n0==0): wave nh==0 -> Q, nh==1 -> K.
        // FULLY unrolled (jh runtime index into acc[][] would force scratch).
        const float* bias_p = nh ? kb : qb;
        u16* dst = nh ? kt : qt;
        u16* reg = ((w & 2) ? Bs : As) + (w & 1) * 4096;  // 32*72=2304 <= 4096
        #pragma unroll
        for (int jh = 0; jh < 2; ++jh) {
            #pragma unroll
            for (int j2 = 0; j2 < 2; ++j2) {
                int j = jh * 2 + j2;
                int t_loc = j2 * 16 + l15;
                #pragma unroll
                for (int i = 0; i < 4; ++i) {
                    ushort4 o;
                    float b0 = bias_p[i * 16 + q * 4 + 0];
                    float b1 = bias_p[i * 16 + q * 4 + 1];
                    float b2 = bias_p[i * 16 + q * 4 + 2];
                    float b3 = bias_p[i * 16 + q * 4 + 3];
                    o.x = f2bf(acc[i][j][0] + b0);
                    o.y = f2bf(acc[i][j][1] + b1);
                    o.z = f2bf(acc[i][j][2] + b2);
                    o.w = f2bf(acc[i][j][3] + b3);
                    *(ushort4*)&reg[t_loc * 72 + i * 16 + q * 4] = o;
                }
            }
            const int cc8 = lane & 7, tb = lane >> 3;
            #pragma unroll
            for (int rr2 = 0; rr2 < 4; ++rr2) {
                int t32 = tb * 4 + rr2;
                bf16x8 vv = *(const bf16x8*)&reg[t32 * 72 + cc8 * 8];
                int t = t0 + th * 64 + jh * 32 + t32;
                *(bf16x8*)(dst + ((size_t)b * Tc + t) * 64 + cc8 * 8) = vv;
            }
            __builtin_amdgcn_wave_barrier();  // order reg reuse across jh
        }
    }
}

// ---------------------------------------------------------------------------
// Kernel D: fused MFMA attention v5 = v4 with the scratch-spill bug fixed:
// the epilogue cg-loop is now FULLY unrolled so every acc[][] index is a
// compile-time constant. (R2–R5: `#pragma unroll 1` + acc[tt][cg] runtime
// index -> alloca in scratch -> every MFMA did load/store to scratch ->
// ~850 MB HBM writes, 192 µs. That was the whole bottleneck.)
// ---------------------------------------------------------------------------
__global__ __launch_bounds__(256, 2) void attn_kernel(
    const float* __restrict__ x,
    const u16* __restrict__ qt, const u16* __restrict__ kt,
    const u16* __restrict__ vc, const float* __restrict__ gp,
    float* __restrict__ out)
{
    const int tid = threadIdx.x, lane = tid & 63, w = tid >> 6;
    const int l15 = lane & 15, q = lane >> 4;
    // XCD swizzle: xcd = l&7; 4 (b,by) combos per XCD; 16 bx each, ids mod 8.
    const int l    = blockIdx.x;           // 0..511
    const int xcd  = l & 7, slot = l >> 3;
    const int combo = xcd * 4 + (slot >> 4);
    const int bx = slot & 15;
    const int b  = combo >> 1;
    const int by = combo & 1;
    const int t0 = bx * 64;
    const int cb = by * 256;

    __shared__ u16   P[2][4][16][40];   // [buf][t-subtile][t'][s pad40] 10 KB
    __shared__ float lrow[64];
    __shared__ float tr2[4][16][68];    // per-wave [c][t] epilogue staging

    // Q B-frags for this wave's t-subtile (t = t0 + w*16 + l15).
    const u16* qp = qt + ((size_t)b * Tc + t0 + w * 16 + l15) * 64 + q * 8;
    const bf16x8 qf0 = *(const bf16x8*)qp;
    const bf16x8 qf1 = *(const bf16x8*)(qp + 32);

    const u16* ktb = kt + (size_t)b * Tc * 64;
    const u16* vbb = vc + ((size_t)(b * Cc + cb + w * 64)) * Tc;

    floatx4 acc[4][4];                  // [tt][cg] — constant-indexed ONLY
    #pragma unroll
    for (int i = 0; i < 4; ++i)
        #pragma unroll
        for (int j = 0; j < 4; ++j) acc[i][j] = (floatx4){0.f, 0.f, 0.f, 0.f};
    float lsum = 0.f;

    int buf = 0;
    #pragma unroll 1
    for (int s0 = 0; s0 < Tc; s0 += 32, buf ^= 1) {
        const u16* kp = ktb + (size_t)(s0 + l15) * 64 + q * 8;
        bf16x8 k00 = *(const bf16x8*)kp;
        bf16x8 k01 = *(const bf16x8*)(kp + 32);
        bf16x8 k10 = *(const bf16x8*)(kp + 1024);
        bf16x8 k11 = *(const bf16x8*)(kp + 1024 + 32);

        bf16x8 vf[4];
        const u16* vp = vbb + (size_t)l15 * Tc + s0 + q * 8;
        #pragma unroll
        for (int cg = 0; cg < 4; ++cg)
            vf[cg] = *(const bf16x8*)(vp + (size_t)cg * 16 * Tc);

        floatx4 e0 = (floatx4){0.f, 0.f, 0.f, 0.f};
        floatx4 e1 = (floatx4){0.f, 0.f, 0.f, 0.f};
        e0 = __builtin_amdgcn_mfma_f32_16x16x32_bf16(k00, qf0, e0, 0, 0, 0);
        e0 = __builtin_amdgcn_mfma_f32_16x16x32_bf16(k01, qf1, e0, 0, 0, 0);
        e1 = __builtin_amdgcn_mfma_f32_16x16x32_bf16(k10, qf0, e1, 0, 0, 0);
        e1 = __builtin_amdgcn_mfma_f32_16x16x32_bf16(k11, qf1, e1, 0, 0, 0);

        float p0[4], p1[4];
        #pragma unroll
        for (int r = 0; r < 4; ++r) { p0[r] = __expf(e0[r]); p1[r] = __expf(e1[r]); }
        lsum += p0[0] + p0[1] + p0[2] + p0[3] + p1[0] + p1[1] + p1[2] + p1[3];

        ushort4 w0 = { f2bf(p0[0]), f2bf(p0[1]), f2bf(p0[2]), f2bf(p0[3]) };
        ushort4 w1 = { f2bf(p1[0]), f2bf(p1[1]), f2bf(p1[2]), f2bf(p1[3]) };
        *(ushort4*)&P[buf][w][l15][q * 4]      = w0;
        *(ushort4*)&P[buf][w][l15][16 + q * 4] = w1;
        __syncthreads();

        #pragma unroll
        for (int tt = 0; tt < 4; ++tt) {
            bf16x8 pf = *(const bf16x8*)&P[buf][tt][l15][q * 8];
            #pragma unroll
            for (int cg = 0; cg < 4; ++cg)
                acc[tt][cg] = __builtin_amdgcn_mfma_f32_16x16x32_bf16(
                    pf, vf[cg], acc[tt][cg], 0, 0, 0);
        }
    }

    // l per t: reduce the 4 disjoint q-partials, share across waves.
    lsum += __shfl_xor(lsum, 16);
    lsum += __shfl_xor(lsum, 32);
    if (lane < 16) lrow[w * 16 + lane] = lsum;
    __syncthreads();

    const float g = gp[0];
    float sc[4][4];
    #pragma unroll
    for (int tt = 0; tt < 4; ++tt)
        #pragma unroll
        for (int rr = 0; rr < 4; ++rr)
            sc[tt][rr] = g / lrow[tt * 16 + q * 4 + rr];

    // Epilogue (FULLY unrolled): per 16c-chunk cg stage [c=l15][t 64], then
    // float4 read + x-add + store (full 128 B lines per instruction).
    const float* xb = x   + ((size_t)(b * Cc + cb + w * 64)) * Tc + t0;
    float*       ob = out + ((size_t)(b * Cc + cb + w * 64)) * Tc + t0;
    #pragma unroll
    for (int cg = 0; cg < 4; ++cg) {
        #pragma unroll
        for (int tt = 0; tt < 4; ++tt) {
            float4 vv;
            vv.x = acc[tt][cg][0] * sc[tt][0];
            vv.y = acc[tt][cg][1] * sc[tt][1];
            vv.z = acc[tt][cg][2] * sc[tt][2];
            vv.w = acc[tt][cg][3] * sc[tt][3];
            *(float4*)&tr2[w][l15][tt * 16 + q * 4] = vv;
        }
        #pragma unroll
        for (int i = 0; i < 4; ++i) {
            int cr = i * 4 + (lane >> 4);       // c within chunk
            int t4 = (lane & 15) * 4;
            float4 vv = *(const float4*)&tr2[w][cr][t4];
            size_t go = (size_t)(cg * 16 + cr) * Tc + t4;
            float4 xv = *(const float4*)(xb + go);
            vv.x += xv.x; vv.y += xv.y; vv.z += xv.z; vv.w += xv.w;
            *(float4*)(ob + go) = vv;
        }
        __builtin_amdgcn_wave_barrier();   // keep write(cg+1) after read(cg)
    }
}

extern "C" void kernel_launch(void* const* d_in, const int* in_sizes, int n_in,
                              void* d_out, int out_size, void* d_ws, size_t ws_size,
                              hipStream_t stream) {
    const float* x     = (const float*)d_in[0];
    const float* qw    = (const float*)d_in[1];
    const float* qbias = (const float*)d_in[2];
    const float* kw    = (const float*)d_in[3];
    const float* kbias = (const float*)d_in[4];
    const float* vw    = (const float*)d_in[5];
    const float* vbias = (const float*)d_in[6];
    const float* gamma = (const float*)d_in[7];
    float* out = (float*)d_out;

    // ws (bf16): wb[640][512] | xt[B*T][512] | qt[B*T][64] | kt[B*T][64] | vc[B][C][T]
    u16* wb = (u16*)d_ws;
    u16* xt = wb + (size_t)640 * 512;
    u16* qt = xt + (size_t)Bc * Tc * Cc;
    u16* kt = qt + (size_t)Bc * Tc * 64;
    u16* vc = kt + (size_t)Bc * Tc * 64;

    wconv_kernel<<<320, 256, 0, stream>>>(qw, kw, vw, wb);
    xtrans_kernel<<<dim3(Tc / 64, Cc / 64, Bc), 256, 0, stream>>>(x, xt);
    proj_kernel<<<dim3(Tc / 128, 5, Bc), 256, 0, stream>>>(
        wb, xt, qbias, kbias, vbias, qt, kt, vc);
    attn_kernel<<<dim3(512), 256, 0, stream>>>(
        x, qt, kt, vc, gamma, out);
}